// Round 6
// baseline (629.580 us; speedup 1.0000x reference)
//
#include <hip/hip_runtime.h>
#include <hip/hip_bf16.h>
#include <hip/hip_fp16.h>
#include <type_traits>

#define N_NODES 100000
#define N_EDGES 1600000

typedef _Float16 half8_t __attribute__((ext_vector_type(8)));
typedef _Float16 half4_t __attribute__((ext_vector_type(4)));
typedef float floatx4 __attribute__((ext_vector_type(4)));

// ---------------------------------------------------------------- CSR build
// XCD-partitioned degree count: partition = blockIdx & 7 (round-robin block->XCD),
// so deg-line atomics stay within one XCD's L2.
__global__ void count_deg_part(const int* __restrict__ dst, int* __restrict__ deg, int E) {
    const int part = blockIdx.x & 7;
    const int sb = blockIdx.x >> 3;
    const int nslices = gridDim.x >> 3;
    const int psz = N_NODES / 8;
    const int lo = part * psz;
    const int hi = (part == 7) ? N_NODES : lo + psz;
    const int begin = (int)((long long)E * sb / nslices);
    const int end = (int)((long long)E * (sb + 1) / nslices);
    for (int i = begin + threadIdx.x; i < end; i += blockDim.x) {
        int d = dst[i];
        if (d >= lo && d < hi) atomicAdd(&deg[d], 1);
    }
}

__global__ void block_sums(const int* __restrict__ deg, int* __restrict__ bsum, int N) {
    __shared__ int ws[4];
    const int t = threadIdx.x;
    int i = blockIdx.x * 256 + t;
    int v = (i < N) ? deg[i] : 0;
    #pragma unroll
    for (int o = 32; o; o >>= 1) v += __shfl_down(v, o, 64);
    if ((t & 63) == 0) ws[t >> 6] = v;
    __syncthreads();
    if (t == 0) bsum[blockIdx.x] = ws[0] + ws[1] + ws[2] + ws[3];
}

__global__ void scan_bsum(int* __restrict__ bsum, int nb) {
    __shared__ int sh[512];
    const int t = threadIdx.x;
    sh[t] = (t < nb) ? bsum[t] : 0;
    __syncthreads();
    for (int o = 1; o < 512; o <<= 1) {
        int v = (t >= o) ? sh[t - o] : 0;
        __syncthreads();
        sh[t] += v;
        __syncthreads();
    }
    if (t < nb) bsum[t] = sh[t];
}

__global__ void scan_final(const int* __restrict__ deg, const int* __restrict__ bsum,
                           int* __restrict__ row_ptr, int* __restrict__ cursor,
                           int* __restrict__ csr_dst, int N) {
    __shared__ int ws[4];
    const int t = threadIdx.x;
    const int b = blockIdx.x;
    const int i = b * 256 + t;
    const int lane = t & 63;
    const int wid = t >> 6;
    int v = (i < N) ? deg[i] : 0;
    int x = v;
    #pragma unroll
    for (int o = 1; o < 64; o <<= 1) {
        int y = __shfl_up(x, o, 64);
        if (lane >= o) x += y;
    }
    if (lane == 63) ws[wid] = x;
    __syncthreads();
    int prefix = (b > 0) ? bsum[b - 1] : 0;
    for (int k = 0; k < wid; ++k) prefix += ws[k];
    if (i < N) {
        int st = prefix + x - v;
        row_ptr[i + 1] = prefix + x;
        cursor[i] = st;
        for (int j = 0; j < v; ++j) csr_dst[st + j] = i;
    }
    if (i == 0) row_ptr[0] = 0;
}

// XCD-partitioned scatter (see R4/R5: kills cross-XCD CSR-line write amplification)
__global__ void scatter_edges_part(const int* __restrict__ src, const int* __restrict__ dst,
                                   int* __restrict__ cursor, int* __restrict__ e_src, int E) {
    const int part = blockIdx.x & 7;
    const int sb = blockIdx.x >> 3;
    const int nslices = gridDim.x >> 3;
    const int psz = N_NODES / 8;
    const int lo = part * psz;
    const int hi = (part == 7) ? N_NODES : lo + psz;
    const int begin = (int)((long long)E * sb / nslices);
    const int end = (int)((long long)E * (sb + 1) / nslices);
    for (int i = begin + threadIdx.x; i < end; i += blockDim.x) {
        int d = dst[i];
        if (d >= lo && d < hi) {
            int p = atomicAdd(&cursor[d], 1);
            e_src[p] = src[i];
        }
    }
}

// ---------------------------------------------------------------- W prep: transpose + fp16
__global__ void prep_w(const float* __restrict__ W1, const float* __restrict__ W2,
                       __half* __restrict__ Wt1, __half* __restrict__ Wt2) {
    const int c = blockIdx.x;
    const int k = threadIdx.x;
    if (c < 128) {
        Wt1[c * 128 + k] = __float2half(W1[k * 128 + c]);
    } else {
        int c2 = c - 128;  // 0..191
        float v = (c2 < 188) ? W2[k * 188 + c2] : 0.f;
        Wt2[c2 * 128 + k] = __float2half(v);
    }
}

// ---------------------------------------------------------------- MFMA GEMM
template <int NTILES, int NLOG, int OSTRIDE, bool PADSTORE, bool GATHER, typename AT>
__global__ __launch_bounds__(256) void gemm_mfma(
    const AT* __restrict__ A, const __half* __restrict__ Wt,
    __half* __restrict__ C, const int* __restrict__ gather, int N) {
    constexpr int LDA = 136;
    __shared__ _Float16 As[64 * LDA];
    __shared__ int ridx[64];
    const int tid = threadIdx.x;
    const int r0 = blockIdx.x * 64;

    if (tid < 64) {
        int row = r0 + tid;
        int pr = 0;
        if (row < N) pr = GATHER ? gather[row] : row;
        ridx[tid] = pr;
    }
    __syncthreads();

    {
        const int r = tid >> 2, q = tid & 3;
        const int src = ridx[r];
        if constexpr (std::is_same<AT, float>::value) {
            const float4* A4 = (const float4*)A;
            #pragma unroll
            for (int i = 0; i < 8; ++i) {
                float4 v = A4[(size_t)src * 32 + q * 8 + i];
                half4_t hv = {(_Float16)v.x, (_Float16)v.y, (_Float16)v.z, (_Float16)v.w};
                *(half4_t*)&As[r * LDA + q * 32 + i * 4] = hv;
            }
        } else {
            const uint4* A4 = (const uint4*)A;
            #pragma unroll
            for (int i = 0; i < 4; ++i) {
                uint4 v = A4[(size_t)src * 16 + q * 4 + i];
                *(uint4*)&As[r * LDA + q * 32 + i * 8] = v;
            }
        }
    }
    __syncthreads();

    const int lane = tid & 63;
    const int wave = tid >> 6;
    const int col = lane & 15;
    const int quad = lane >> 4;
    const int arow = wave * 16 + col;

    floatx4 acc[NTILES];
    #pragma unroll
    for (int t = 0; t < NTILES; ++t) acc[t] = (floatx4){0.f, 0.f, 0.f, 0.f};

    #pragma unroll
    for (int kc = 0; kc < 4; ++kc) {
        half8_t a = *(const half8_t*)&As[arow * LDA + kc * 32 + quad * 8];
        #pragma unroll
        for (int t = 0; t < NTILES; ++t) {
            half8_t b = *(const half8_t*)&Wt[(size_t)(t * 16 + col) * 128 + kc * 32 + quad * 8];
            acc[t] = __builtin_amdgcn_mfma_f32_16x16x32_f16(a, b, acc[t], 0, 0, 0);
        }
    }

    #pragma unroll
    for (int t = 0; t < NTILES; ++t) {
        #pragma unroll
        for (int r = 0; r < 4; ++r) {
            int row = r0 + wave * 16 + quad * 4 + r;
            int c = t * 16 + col;
            if (row < N && c < NLOG) {
                int sc = PADSTORE ? (c + c / 47) : c;
                C[(size_t)row * OSTRIDE + sc] = __float2half(acc[t][r]);
            }
        }
    }
}

// ---------------------------------------------------------------- per-node attention dots
template <int H, int D, int HD, int HDP, int P2>
__global__ void compute_elr(const __half* __restrict__ feat, const float* __restrict__ al,
                            const float* __restrict__ ar, float* __restrict__ el,
                            float* __restrict__ er) {
    const int n = blockIdx.x;
    const int t = threadIdx.x;
    __shared__ float sa[HDP], sb[HDP];
    float f = 0.f, a = 0.f, b = 0.f;
    if (t < HD) {
        f = __half2float(feat[(size_t)n * HD + t]);
        a = al[t];
        b = ar[t];
    }
    sa[t] = f * a;
    sb[t] = f * b;
    for (int s = P2 / 2; s >= 1; s >>= 1) {
        __syncthreads();
        if (t < HD) {
            int d = t % D;
            if (d < s && d + s < D) {
                sa[t] += sa[t + s];
                sb[t] += sb[t + s];
            }
        }
    }
    __syncthreads();
    if (t < HD && (t % D) == 0) {
        int h = t / D;
        el[n * H + h] = sa[t];
        er[n * H + h] = sb[t];
    }
}

__global__ void compute_elr2(const __half* __restrict__ feat, const float* __restrict__ al,
                             const float* __restrict__ ar, float* __restrict__ el,
                             float* __restrict__ er) {
    const int n = blockIdx.x;
    const int t = threadIdx.x;
    __shared__ float sa[192], sb[192];
    float f = 0.f, a = 0.f, b = 0.f;
    if (t < 188) {
        int h = t / 47, d = t - h * 47;
        f = __half2float(feat[(size_t)n * 192 + h * 48 + d]);
        a = al[t];
        b = ar[t];
    }
    sa[t] = f * a;
    sb[t] = f * b;
    for (int s = 32; s >= 1; s >>= 1) {
        __syncthreads();
        if (t < 188) {
            int d = t % 47;
            if (d < s && d + s < 47) {
                sa[t] += sa[t + s];
                sb[t] += sb[t + s];
            }
        }
    }
    __syncthreads();
    if (t < 188 && (t % 47) == 0) {
        int h = t / 47;
        el[n * 4 + h] = sa[t];
        er[n * 4 + h] = sb[t];
    }
}

// ---------------------------------------------------------------- per-edge attention weights
// transposed output: ewt[h*E + i] so gathers can vector-load a head's weight run
__global__ void edge_weights(const int* __restrict__ e_src, const int* __restrict__ csr_dst,
                             const float* __restrict__ el, const float* __restrict__ er,
                             __half* __restrict__ ewt, int E) {
    int i = blockIdx.x * blockDim.x + threadIdx.x;
    if (i >= E) return;
    int s = e_src[i], d = csr_dst[i];
    float4 a = ((const float4*)el)[s];
    float4 b = ((const float4*)er)[d];
    float e0 = a.x + b.x; e0 = (e0 > 0.f) ? e0 : 0.2f * e0;
    float e1 = a.y + b.y; e1 = (e1 > 0.f) ? e1 : 0.2f * e1;
    float e2 = a.z + b.z; e2 = (e2 > 0.f) ? e2 : 0.2f * e2;
    float e3 = a.w + b.w; e3 = (e3 > 0.f) ? e3 : 0.2f * e3;
    ewt[0 * E + i] = __float2half(__expf(e0));
    ewt[1 * E + i] = __float2half(__expf(e1));
    ewt[2 * E + i] = __float2half(__expf(e2));
    ewt[3 * E + i] = __float2half(__expf(e3));
}

// ---------------------------------------------------------------- layer-1 gather: wave/node, 64 lanes x half2
__global__ __launch_bounds__(256) void gat_gather1(
    const __half* __restrict__ feat, const __half* __restrict__ ewt,
    const int* __restrict__ row_ptr, const int* __restrict__ e_src,
    const float* __restrict__ bias, __half* __restrict__ out) {
    const int t = threadIdx.x;
    const int lane = t & 63;
    const int n = blockIdx.x * 4 + (t >> 6);
    const int h = lane >> 4;
    const int start = row_ptr[n], end = row_ptr[n + 1];
    const __half2* f2 = (const __half2*)feat;
    const __half* wh = ewt + (size_t)h * N_EDGES;
    float ax = 0.f, ay = 0.f, s = 0.f;
    int i = start;
    for (; i < end && (i & 3); ++i) {             // peel to 4-alignment
        float ww = __half2float(wh[i]);
        float2 g = __half22float2(f2[e_src[i] * 64 + lane]);
        s += ww; ax = fmaf(ww, g.x, ax); ay = fmaf(ww, g.y, ay);
    }
    for (; i + 8 <= end; i += 8) {
        int4 sa = *(const int4*)&e_src[i];
        int4 sb = *(const int4*)&e_src[i + 4];
        half4_t w0 = *(const half4_t*)&wh[i];
        half4_t w1 = *(const half4_t*)&wh[i + 4];
        __half2 f[8];
        f[0] = f2[sa.x * 64 + lane]; f[1] = f2[sa.y * 64 + lane];
        f[2] = f2[sa.z * 64 + lane]; f[3] = f2[sa.w * 64 + lane];
        f[4] = f2[sb.x * 64 + lane]; f[5] = f2[sb.y * 64 + lane];
        f[6] = f2[sb.z * 64 + lane]; f[7] = f2[sb.w * 64 + lane];
        #pragma unroll
        for (int j = 0; j < 4; ++j) {
            float wj = (float)w0[j];
            float2 g = __half22float2(f[j]);
            s += wj; ax = fmaf(wj, g.x, ax); ay = fmaf(wj, g.y, ay);
        }
        #pragma unroll
        for (int j = 0; j < 4; ++j) {
            float wj = (float)w1[j];
            float2 g = __half22float2(f[4 + j]);
            s += wj; ax = fmaf(wj, g.x, ax); ay = fmaf(wj, g.y, ay);
        }
    }
    for (; i + 4 <= end; i += 4) {
        int4 sa = *(const int4*)&e_src[i];
        half4_t w0 = *(const half4_t*)&wh[i];
        __half2 f[4];
        f[0] = f2[sa.x * 64 + lane]; f[1] = f2[sa.y * 64 + lane];
        f[2] = f2[sa.z * 64 + lane]; f[3] = f2[sa.w * 64 + lane];
        #pragma unroll
        for (int j = 0; j < 4; ++j) {
            float wj = (float)w0[j];
            float2 g = __half22float2(f[j]);
            s += wj; ax = fmaf(wj, g.x, ax); ay = fmaf(wj, g.y, ay);
        }
    }
    for (; i < end; ++i) {
        float ww = __half2float(wh[i]);
        float2 g = __half22float2(f2[e_src[i] * 64 + lane]);
        s += ww; ax = fmaf(ww, g.x, ax); ay = fmaf(ww, g.y, ay);
    }
    float inv = 1.f / fmaxf(s, 1e-9f);
    float ox = ax * inv + bias[lane * 2 + 0];
    float oy = ay * inv + bias[lane * 2 + 1];
    ox = (ox > 0.f) ? ox : (__expf(ox) - 1.f);
    oy = (oy > 0.f) ? oy : (__expf(oy) - 1.f);
    ((__half2*)out)[(size_t)n * 64 + lane] = __floats2half2_rn(ox, oy);
}

// ---------------------------------------------------------------- layer-2 gather: wave/node, 48 lanes x half4
__global__ __launch_bounds__(256) void gat_gather2(
    const __half* __restrict__ feat, const __half* __restrict__ ewt,
    const int* __restrict__ row_ptr, const int* __restrict__ e_src,
    const float* __restrict__ bias, float* __restrict__ out) {
    const int t = threadIdx.x;
    const int lane = t & 63;
    const int n = blockIdx.x * 4 + (t >> 6);
    if (lane < 48) {
        const int h = lane / 12;
        const int q = lane - h * 12;
        const int start = row_ptr[n], end = row_ptr[n + 1];
        const half4_t* f4 = (const half4_t*)feat;
        const __half* wh = ewt + (size_t)h * N_EDGES;
        float a0 = 0.f, a1 = 0.f, a2 = 0.f, a3 = 0.f, s = 0.f;
        int i = start;
        for (; i < end && (i & 3); ++i) {         // peel to 4-alignment
            float ww = __half2float(wh[i]);
            half4_t f0 = f4[e_src[i] * 48 + lane];
            s += ww;
            a0 = fmaf(ww, (float)f0[0], a0); a1 = fmaf(ww, (float)f0[1], a1);
            a2 = fmaf(ww, (float)f0[2], a2); a3 = fmaf(ww, (float)f0[3], a3);
        }
        for (; i + 8 <= end; i += 8) {
            int4 sa = *(const int4*)&e_src[i];
            int4 sb = *(const int4*)&e_src[i + 4];
            half4_t w0 = *(const half4_t*)&wh[i];
            half4_t w1 = *(const half4_t*)&wh[i + 4];
            half4_t f[8];
            f[0] = f4[sa.x * 48 + lane]; f[1] = f4[sa.y * 48 + lane];
            f[2] = f4[sa.z * 48 + lane]; f[3] = f4[sa.w * 48 + lane];
            f[4] = f4[sb.x * 48 + lane]; f[5] = f4[sb.y * 48 + lane];
            f[6] = f4[sb.z * 48 + lane]; f[7] = f4[sb.w * 48 + lane];
            #pragma unroll
            for (int j = 0; j < 4; ++j) {
                float wj = (float)w0[j];
                s += wj;
                a0 = fmaf(wj, (float)f[j][0], a0); a1 = fmaf(wj, (float)f[j][1], a1);
                a2 = fmaf(wj, (float)f[j][2], a2); a3 = fmaf(wj, (float)f[j][3], a3);
            }
            #pragma unroll
            for (int j = 0; j < 4; ++j) {
                float wj = (float)w1[j];
                s += wj;
                a0 = fmaf(wj, (float)f[4 + j][0], a0); a1 = fmaf(wj, (float)f[4 + j][1], a1);
                a2 = fmaf(wj, (float)f[4 + j][2], a2); a3 = fmaf(wj, (float)f[4 + j][3], a3);
            }
        }
        for (; i + 4 <= end; i += 4) {
            int4 sa = *(const int4*)&e_src[i];
            half4_t w0 = *(const half4_t*)&wh[i];
            half4_t f[4];
            f[0] = f4[sa.x * 48 + lane]; f[1] = f4[sa.y * 48 + lane];
            f[2] = f4[sa.z * 48 + lane]; f[3] = f4[sa.w * 48 + lane];
            #pragma unroll
            for (int j = 0; j < 4; ++j) {
                float wj = (float)w0[j];
                s += wj;
                a0 = fmaf(wj, (float)f[j][0], a0); a1 = fmaf(wj, (float)f[j][1], a1);
                a2 = fmaf(wj, (float)f[j][2], a2); a3 = fmaf(wj, (float)f[j][3], a3);
            }
        }
        for (; i < end; ++i) {
            float ww = __half2float(wh[i]);
            half4_t f0 = f4[e_src[i] * 48 + lane];
            s += ww;
            a0 = fmaf(ww, (float)f0[0], a0); a1 = fmaf(ww, (float)f0[1], a1);
            a2 = fmaf(ww, (float)f0[2], a2); a3 = fmaf(ww, (float)f0[3], a3);
        }
        if (q == 11) a3 = 0.f;                    // storage pad col — mask
        float inv = 1.f / fmaxf(s, 1e-9f);
        const int d0 = q * 4;
        float b0 = bias[h * 47 + d0 + 0];
        float b1 = bias[h * 47 + d0 + 1];
        float b2 = bias[h * 47 + d0 + 2];
        float b3 = (d0 + 3 < 47) ? bias[h * 47 + d0 + 3] : 0.f;
        float r0 = a0 * inv + b0;
        float r1 = a1 * inv + b1;
        float r2 = a2 * inv + b2;
        float r3 = a3 * inv + b3;
        float t0 = r0 + __shfl(r0, lane + 12, 64) + __shfl(r0, lane + 24, 64) + __shfl(r0, lane + 36, 64);
        float t1 = r1 + __shfl(r1, lane + 12, 64) + __shfl(r1, lane + 24, 64) + __shfl(r1, lane + 36, 64);
        float t2 = r2 + __shfl(r2, lane + 12, 64) + __shfl(r2, lane + 24, 64) + __shfl(r2, lane + 36, 64);
        float t3 = r3 + __shfl(r3, lane + 12, 64) + __shfl(r3, lane + 24, 64) + __shfl(r3, lane + 36, 64);
        if (h == 0) {
            size_t base = (size_t)n * 47 + d0;
            out[base + 0] = 0.25f * t0;
            out[base + 1] = 0.25f * t1;
            out[base + 2] = 0.25f * t2;
            if (d0 + 3 < 47) out[base + 3] = 0.25f * t3;
        }
    }
}

// ---------------------------------------------------------------- launcher
extern "C" void kernel_launch(void* const* d_in, const int* in_sizes, int n_in,
                              void* d_out, int out_size, void* d_ws, size_t ws_size,
                              hipStream_t stream) {
    const int N = N_NODES, E = N_EDGES;
    const float* x    = (const float*)d_in[0];
    const int*   src  = (const int*)d_in[1];
    const int*   dst  = (const int*)d_in[2];
    const int*   inv  = (const int*)d_in[3];
    const float* W1   = (const float*)d_in[4];
    const float* al1  = (const float*)d_in[5];
    const float* ar1  = (const float*)d_in[6];
    const float* b1   = (const float*)d_in[7];
    const float* W2   = (const float*)d_in[8];
    const float* al2  = (const float*)d_in[9];
    const float* ar2  = (const float*)d_in[10];
    const float* b2   = (const float*)d_in[11];
    float* out = (float*)d_out;

    char* p = (char*)d_ws;
    auto carve = [&](size_t bytes) {
        char* q = p;
        p += (bytes + 255) & ~size_t(255);
        return q;
    };
    __half* feat1   = (__half*)carve((size_t)N * 128 * 2);
    __half* feat2   = (__half*)carve((size_t)N * 192 * 2);
    __half* hbuf    = (__half*)carve((size_t)N * 128 * 2);
    __half* Wt1     = (__half*)carve(128 * 128 * 2);
    __half* Wt2     = (__half*)carve(192 * 128 * 2);
    float*  el      = (float*)carve((size_t)N * 4 * 4);
    float*  er      = (float*)carve((size_t)N * 4 * 4);
    int*    deg     = (int*)carve((size_t)N * 4);
    int*    row_ptr = (int*)carve((size_t)(N + 1) * 4);
    int*    cursor  = (int*)carve((size_t)N * 4);
    int*    bsum    = (int*)carve(512 * 4);
    int*    e_src   = (int*)carve((size_t)E * 4);
    int*    csr_dst = (int*)carve((size_t)E * 4);
    __half* ewt     = (__half*)carve((size_t)E * 4 * 2);   // 4 per-head streams of E halfs

    const int nb = (N + 255) / 256;  // 391

    // ---- CSR build ----
    hipMemsetAsync(deg, 0, (size_t)N * 4, stream);
    count_deg_part<<<2048, 256, 0, stream>>>(dst, deg, E);
    block_sums<<<nb, 256, 0, stream>>>(deg, bsum, N);
    scan_bsum<<<1, 512, 0, stream>>>(bsum, nb);
    scan_final<<<nb, 256, 0, stream>>>(deg, bsum, row_ptr, cursor, csr_dst, N);
    scatter_edges_part<<<2048, 256, 0, stream>>>(src, dst, cursor, e_src, E);

    // ---- weight prep ----
    prep_w<<<320, 128, 0, stream>>>(W1, W2, Wt1, Wt2);

    // ---- layer 1 ----
    gemm_mfma<8, 128, 128, false, false, float><<<(N + 63) / 64, 256, 0, stream>>>(x, Wt1, feat1, nullptr, N);
    compute_elr<4, 32, 128, 128, 32><<<N, 128, 0, stream>>>(feat1, al1, ar1, el, er);
    edge_weights<<<(E + 255) / 256, 256, 0, stream>>>(e_src, csr_dst, el, er, ewt, E);
    gat_gather1<<<(N + 3) / 4, 256, 0, stream>>>(feat1, ewt, row_ptr, e_src, b1, hbuf);

    // ---- layer 2 (rows gathered through inverse_idx) ----
    gemm_mfma<12, 188, 192, true, true, __half><<<(N + 63) / 64, 256, 0, stream>>>(hbuf, Wt2, feat2, inv, N);
    compute_elr2<<<N, 192, 0, stream>>>(feat2, al2, ar2, el, er);
    edge_weights<<<(E + 255) / 256, 256, 0, stream>>>(e_src, csr_dst, el, er, ewt, E);
    gat_gather2<<<(N + 3) / 4, 256, 0, stream>>>(feat2, ewt, row_ptr, e_src, b2, out);
}

// Round 7
// 581.645 us; speedup vs baseline: 1.0824x; 1.0824x over previous
//
#include <hip/hip_runtime.h>
#include <hip/hip_bf16.h>
#include <hip/hip_fp16.h>
#include <type_traits>

#define N_NODES 100000
#define N_EDGES 1600000

typedef _Float16 half8_t __attribute__((ext_vector_type(8)));
typedef _Float16 half4_t __attribute__((ext_vector_type(4)));
typedef float floatx4 __attribute__((ext_vector_type(4)));

// ---------------------------------------------------------------- CSR build
__global__ void count_deg(const int* __restrict__ dst, int* __restrict__ deg, int E) {
    int i = blockIdx.x * blockDim.x + threadIdx.x;
    if (i < E) atomicAdd(&deg[dst[i]], 1);
}

__global__ void block_sums(const int* __restrict__ deg, int* __restrict__ bsum, int N) {
    __shared__ int ws[4];
    const int t = threadIdx.x;
    int i = blockIdx.x * 256 + t;
    int v = (i < N) ? deg[i] : 0;
    #pragma unroll
    for (int o = 32; o; o >>= 1) v += __shfl_down(v, o, 64);
    if ((t & 63) == 0) ws[t >> 6] = v;
    __syncthreads();
    if (t == 0) bsum[blockIdx.x] = ws[0] + ws[1] + ws[2] + ws[3];
}

__global__ void scan_bsum(int* __restrict__ bsum, int nb) {
    __shared__ int sh[512];
    const int t = threadIdx.x;
    sh[t] = (t < nb) ? bsum[t] : 0;
    __syncthreads();
    for (int o = 1; o < 512; o <<= 1) {
        int v = (t >= o) ? sh[t - o] : 0;
        __syncthreads();
        sh[t] += v;
        __syncthreads();
    }
    if (t < nb) bsum[t] = sh[t];
}

__global__ void scan_final(const int* __restrict__ deg, const int* __restrict__ bsum,
                           int* __restrict__ row_ptr, int* __restrict__ cursor,
                           int* __restrict__ csr_dst, int N) {
    __shared__ int ws[4];
    const int t = threadIdx.x;
    const int b = blockIdx.x;
    const int i = b * 256 + t;
    const int lane = t & 63;
    const int wid = t >> 6;
    int v = (i < N) ? deg[i] : 0;
    int x = v;
    #pragma unroll
    for (int o = 1; o < 64; o <<= 1) {
        int y = __shfl_up(x, o, 64);
        if (lane >= o) x += y;
    }
    if (lane == 63) ws[wid] = x;
    __syncthreads();
    int prefix = (b > 0) ? bsum[b - 1] : 0;
    for (int k = 0; k < wid; ++k) prefix += ws[k];
    if (i < N) {
        int st = prefix + x - v;
        row_ptr[i + 1] = prefix + x;
        cursor[i] = st;
        for (int j = 0; j < v; ++j) csr_dst[st + j] = i;
    }
    if (i == 0) row_ptr[0] = 0;
}

// XCD-partitioned scatter (R4→R5 measured win: kills cross-XCD CSR-line write amplification)
__global__ void scatter_edges_part(const int* __restrict__ src, const int* __restrict__ dst,
                                   int* __restrict__ cursor, int* __restrict__ e_src, int E) {
    const int part = blockIdx.x & 7;
    const int sb = blockIdx.x >> 3;
    const int nslices = gridDim.x >> 3;
    const int psz = N_NODES / 8;
    const int lo = part * psz;
    const int hi = (part == 7) ? N_NODES : lo + psz;
    const int begin = (int)((long long)E * sb / nslices);
    const int end = (int)((long long)E * (sb + 1) / nslices);
    for (int i = begin + threadIdx.x; i < end; i += blockDim.x) {
        int d = dst[i];
        if (d >= lo && d < hi) {
            int p = atomicAdd(&cursor[d], 1);
            e_src[p] = src[i];
        }
    }
}

// ---------------------------------------------------------------- W prep: transpose + fp16
__global__ void prep_w(const float* __restrict__ W1, const float* __restrict__ W2,
                       __half* __restrict__ Wt1, __half* __restrict__ Wt2) {
    const int c = blockIdx.x;
    const int k = threadIdx.x;
    if (c < 128) {
        Wt1[c * 128 + k] = __float2half(W1[k * 128 + c]);
    } else {
        int c2 = c - 128;  // 0..191
        float v = (c2 < 188) ? W2[k * 188 + c2] : 0.f;
        Wt2[c2 * 128 + k] = __float2half(v);
    }
}

// ---------------------------------------------------------------- MFMA GEMM
template <int NTILES, int NLOG, int OSTRIDE, bool PADSTORE, bool GATHER, typename AT>
__global__ __launch_bounds__(256) void gemm_mfma(
    const AT* __restrict__ A, const __half* __restrict__ Wt,
    __half* __restrict__ C, const int* __restrict__ gather, int N) {
    constexpr int LDA = 136;
    __shared__ _Float16 As[64 * LDA];
    __shared__ int ridx[64];
    const int tid = threadIdx.x;
    const int r0 = blockIdx.x * 64;

    if (tid < 64) {
        int row = r0 + tid;
        int pr = 0;
        if (row < N) pr = GATHER ? gather[row] : row;
        ridx[tid] = pr;
    }
    __syncthreads();

    {
        const int r = tid >> 2, q = tid & 3;
        const int src = ridx[r];
        if constexpr (std::is_same<AT, float>::value) {
            const float4* A4 = (const float4*)A;
            #pragma unroll
            for (int i = 0; i < 8; ++i) {
                float4 v = A4[(size_t)src * 32 + q * 8 + i];
                half4_t hv = {(_Float16)v.x, (_Float16)v.y, (_Float16)v.z, (_Float16)v.w};
                *(half4_t*)&As[r * LDA + q * 32 + i * 4] = hv;
            }
        } else {
            const uint4* A4 = (const uint4*)A;
            #pragma unroll
            for (int i = 0; i < 4; ++i) {
                uint4 v = A4[(size_t)src * 16 + q * 4 + i];
                *(uint4*)&As[r * LDA + q * 32 + i * 8] = v;
            }
        }
    }
    __syncthreads();

    const int lane = tid & 63;
    const int wave = tid >> 6;
    const int col = lane & 15;
    const int quad = lane >> 4;
    const int arow = wave * 16 + col;

    floatx4 acc[NTILES];
    #pragma unroll
    for (int t = 0; t < NTILES; ++t) acc[t] = (floatx4){0.f, 0.f, 0.f, 0.f};

    #pragma unroll
    for (int kc = 0; kc < 4; ++kc) {
        half8_t a = *(const half8_t*)&As[arow * LDA + kc * 32 + quad * 8];
        #pragma unroll
        for (int t = 0; t < NTILES; ++t) {
            half8_t b = *(const half8_t*)&Wt[(size_t)(t * 16 + col) * 128 + kc * 32 + quad * 8];
            acc[t] = __builtin_amdgcn_mfma_f32_16x16x32_f16(a, b, acc[t], 0, 0, 0);
        }
    }

    #pragma unroll
    for (int t = 0; t < NTILES; ++t) {
        #pragma unroll
        for (int r = 0; r < 4; ++r) {
            int row = r0 + wave * 16 + quad * 4 + r;
            int c = t * 16 + col;
            if (row < N && c < NLOG) {
                int sc = PADSTORE ? (c + c / 47) : c;
                C[(size_t)row * OSTRIDE + sc] = __float2half(acc[t][r]);
            }
        }
    }
}

// ---------------------------------------------------------------- per-node attention dots (wave-per-node)
// layer 1: feat1 [n][128]; lane covers dims {2l, 2l+1}; head = lane>>4; shfl-xor reduce over 16 lanes
__global__ __launch_bounds__(256) void elr1_wave(
    const __half* __restrict__ feat, const float* __restrict__ al, const float* __restrict__ ar,
    float* __restrict__ el, float* __restrict__ er) {
    const int t = threadIdx.x;
    const int lane = t & 63;
    const int n = blockIdx.x * 4 + (t >> 6);
    const __half2* f2 = (const __half2*)feat;
    float2 g = __half22float2(f2[(size_t)n * 64 + lane]);
    float2 a = ((const float2*)al)[lane];
    float2 b = ((const float2*)ar)[lane];
    float sl = g.x * a.x + g.y * a.y;
    float sr = g.x * b.x + g.y * b.y;
    #pragma unroll
    for (int o = 1; o < 16; o <<= 1) {
        sl += __shfl_xor(sl, o, 64);
        sr += __shfl_xor(sr, o, 64);
    }
    if ((lane & 15) == 0) {
        int h = lane >> 4;
        el[n * 4 + h] = sl;
        er[n * 4 + h] = sr;
    }
}

// layer 2: feat2 padded [n][192] (storage h*48+d); lane<48 covers half4; head = lane/12;
// tree-reduce within the 12-lane group (strides 6,3, then +1,+2)
__global__ __launch_bounds__(256) void elr2_wave(
    const __half* __restrict__ feat, const float* __restrict__ al, const float* __restrict__ ar,
    float* __restrict__ el, float* __restrict__ er) {
    const int t = threadIdx.x;
    const int lane = t & 63;
    const int n = blockIdx.x * 4 + (t >> 6);
    float sl = 0.f, sr = 0.f;
    int h = 0, q = 0;
    if (lane < 48) {
        h = lane / 12;
        q = lane - h * 12;
        const half4_t* f4 = (const half4_t*)feat;
        half4_t g = f4[(size_t)n * 48 + lane];
        const int d0 = q * 4;
        #pragma unroll
        for (int j = 0; j < 4; ++j) {
            int d = d0 + j;
            if (d < 47) {
                float gv = (float)g[j];
                sl = fmaf(gv, al[h * 47 + d], sl);
                sr = fmaf(gv, ar[h * 47 + d], sr);
            }
        }
    }
    // all lanes execute shfls (wave-synchronous); garbage beyond group unused
    sl += __shfl(sl, lane + 6, 64);
    sr += __shfl(sr, lane + 6, 64);
    sl += __shfl(sl, lane + 3, 64);
    sr += __shfl(sr, lane + 3, 64);
    float l1 = __shfl(sl, lane + 1, 64), l2 = __shfl(sl, lane + 2, 64);
    float r1 = __shfl(sr, lane + 1, 64), r2 = __shfl(sr, lane + 2, 64);
    sl += l1 + l2;
    sr += r1 + r2;
    if (lane < 48 && q == 0) {
        el[n * 4 + h] = sl;
        er[n * 4 + h] = sr;
    }
}

// ---------------------------------------------------------------- per-edge attention weights (CSR order, interleaved fp16)
__global__ void edge_weights(const int* __restrict__ e_src, const int* __restrict__ csr_dst,
                             const float* __restrict__ el, const float* __restrict__ er,
                             __half* __restrict__ w, int E) {
    int i = blockIdx.x * blockDim.x + threadIdx.x;
    if (i >= E) return;
    int s = e_src[i], d = csr_dst[i];
    float4 a = ((const float4*)el)[s];
    float4 b = ((const float4*)er)[d];
    float e0 = a.x + b.x; e0 = (e0 > 0.f) ? e0 : 0.2f * e0;
    float e1 = a.y + b.y; e1 = (e1 > 0.f) ? e1 : 0.2f * e1;
    float e2 = a.z + b.z; e2 = (e2 > 0.f) ? e2 : 0.2f * e2;
    float e3 = a.w + b.w; e3 = (e3 > 0.f) ? e3 : 0.2f * e3;
    __half2* w2 = (__half2*)w;
    w2[i * 2 + 0] = __floats2half2_rn(__expf(e0), __expf(e1));
    w2[i * 2 + 1] = __floats2half2_rn(__expf(e2), __expf(e3));
}

// ---------------------------------------------------------------- layer-1 gather (R5 measured-best form)
__global__ __launch_bounds__(256) void gat_gather1(
    const __half* __restrict__ feat, const __half* __restrict__ w,
    const int* __restrict__ row_ptr, const int* __restrict__ e_src,
    const float* __restrict__ bias, __half* __restrict__ out) {
    const int t = threadIdx.x;
    const int lane = t & 63;
    const int n = blockIdx.x * 4 + (t >> 6);
    const int h = lane >> 4;
    const int start = row_ptr[n], end = row_ptr[n + 1];
    const __half2* f2 = (const __half2*)feat;
    float ax = 0.f, ay = 0.f, s = 0.f;
    int i = start;
    for (; i + 4 <= end; i += 4) {
        int sv0 = e_src[i + 0], sv1 = e_src[i + 1], sv2 = e_src[i + 2], sv3 = e_src[i + 3];
        float w0 = __half2float(w[(i + 0) * 4 + h]);
        float w1 = __half2float(w[(i + 1) * 4 + h]);
        float w2 = __half2float(w[(i + 2) * 4 + h]);
        float w3 = __half2float(w[(i + 3) * 4 + h]);
        __half2 f0 = f2[(size_t)sv0 * 64 + lane];
        __half2 f1 = f2[(size_t)sv1 * 64 + lane];
        __half2 f2v = f2[(size_t)sv2 * 64 + lane];
        __half2 f3 = f2[(size_t)sv3 * 64 + lane];
        float2 g0 = __half22float2(f0), g1 = __half22float2(f1);
        float2 g2 = __half22float2(f2v), g3 = __half22float2(f3);
        s += (w0 + w1) + (w2 + w3);
        ax += w0 * g0.x + w1 * g1.x + w2 * g2.x + w3 * g3.x;
        ay += w0 * g0.y + w1 * g1.y + w2 * g2.y + w3 * g3.y;
    }
    for (; i < end; ++i) {
        int sv = e_src[i];
        float ww = __half2float(w[i * 4 + h]);
        float2 g = __half22float2(f2[(size_t)sv * 64 + lane]);
        s += ww;
        ax += ww * g.x;
        ay += ww * g.y;
    }
    float inv = 1.f / fmaxf(s, 1e-9f);
    float ox = ax * inv + bias[lane * 2 + 0];
    float oy = ay * inv + bias[lane * 2 + 1];
    ox = (ox > 0.f) ? ox : (__expf(ox) - 1.f);
    oy = (oy > 0.f) ? oy : (__expf(oy) - 1.f);
    ((__half2*)out)[(size_t)n * 64 + lane] = __floats2half2_rn(ox, oy);
}

// ---------------------------------------------------------------- layer-2 gather (R5 measured-best form)
__global__ __launch_bounds__(256) void gat_gather2(
    const __half* __restrict__ feat, const __half* __restrict__ w,
    const int* __restrict__ row_ptr, const int* __restrict__ e_src,
    const float* __restrict__ bias, float* __restrict__ out) {
    const int t = threadIdx.x;
    const int lane = t & 63;
    const int n = blockIdx.x * 4 + (t >> 6);
    if (lane < 48) {
        const int h = lane / 12;
        const int q = lane - h * 12;
        const int start = row_ptr[n], end = row_ptr[n + 1];
        const half4_t* f4 = (const half4_t*)feat;
        float a0 = 0.f, a1 = 0.f, a2 = 0.f, a3 = 0.f, s = 0.f;
        int i = start;
        for (; i + 4 <= end; i += 4) {
            int sv0 = e_src[i + 0], sv1 = e_src[i + 1], sv2 = e_src[i + 2], sv3 = e_src[i + 3];
            float w0 = __half2float(w[(i + 0) * 4 + h]);
            float w1 = __half2float(w[(i + 1) * 4 + h]);
            float w2 = __half2float(w[(i + 2) * 4 + h]);
            float w3 = __half2float(w[(i + 3) * 4 + h]);
            half4_t f0 = f4[(size_t)sv0 * 48 + lane];
            half4_t f1 = f4[(size_t)sv1 * 48 + lane];
            half4_t f2 = f4[(size_t)sv2 * 48 + lane];
            half4_t f3 = f4[(size_t)sv3 * 48 + lane];
            s += (w0 + w1) + (w2 + w3);
            a0 += w0 * (float)f0[0] + w1 * (float)f1[0] + w2 * (float)f2[0] + w3 * (float)f3[0];
            a1 += w0 * (float)f0[1] + w1 * (float)f1[1] + w2 * (float)f2[1] + w3 * (float)f3[1];
            a2 += w0 * (float)f0[2] + w1 * (float)f1[2] + w2 * (float)f2[2] + w3 * (float)f3[2];
            a3 += w0 * (float)f0[3] + w1 * (float)f1[3] + w2 * (float)f2[3] + w3 * (float)f3[3];
        }
        for (; i < end; ++i) {
            int sv = e_src[i];
            float ww = __half2float(w[i * 4 + h]);
            half4_t f0 = f4[(size_t)sv * 48 + lane];
            s += ww;
            a0 += ww * (float)f0[0];
            a1 += ww * (float)f0[1];
            a2 += ww * (float)f0[2];
            a3 += ww * (float)f0[3];
        }
        if (q == 11) a3 = 0.f;
        float inv = 1.f / fmaxf(s, 1e-9f);
        const int d0 = q * 4;
        float b0 = bias[h * 47 + d0 + 0];
        float b1 = bias[h * 47 + d0 + 1];
        float b2 = bias[h * 47 + d0 + 2];
        float b3 = (d0 + 3 < 47) ? bias[h * 47 + d0 + 3] : 0.f;
        float r0 = a0 * inv + b0;
        float r1 = a1 * inv + b1;
        float r2 = a2 * inv + b2;
        float r3 = a3 * inv + b3;
        float t0 = r0 + __shfl(r0, lane + 12, 64) + __shfl(r0, lane + 24, 64) + __shfl(r0, lane + 36, 64);
        float t1 = r1 + __shfl(r1, lane + 12, 64) + __shfl(r1, lane + 24, 64) + __shfl(r1, lane + 36, 64);
        float t2 = r2 + __shfl(r2, lane + 12, 64) + __shfl(r2, lane + 24, 64) + __shfl(r2, lane + 36, 64);
        float t3 = r3 + __shfl(r3, lane + 12, 64) + __shfl(r3, lane + 24, 64) + __shfl(r3, lane + 36, 64);
        if (h == 0) {
            size_t base = (size_t)n * 47 + d0;
            out[base + 0] = 0.25f * t0;
            out[base + 1] = 0.25f * t1;
            out[base + 2] = 0.25f * t2;
            if (d0 + 3 < 47) out[base + 3] = 0.25f * t3;
        }
    }
}

// ---------------------------------------------------------------- launcher
extern "C" void kernel_launch(void* const* d_in, const int* in_sizes, int n_in,
                              void* d_out, int out_size, void* d_ws, size_t ws_size,
                              hipStream_t stream) {
    const int N = N_NODES, E = N_EDGES;
    const float* x    = (const float*)d_in[0];
    const int*   src  = (const int*)d_in[1];
    const int*   dst  = (const int*)d_in[2];
    const int*   inv  = (const int*)d_in[3];
    const float* W1   = (const float*)d_in[4];
    const float* al1  = (const float*)d_in[5];
    const float* ar1  = (const float*)d_in[6];
    const float* b1   = (const float*)d_in[7];
    const float* W2   = (const float*)d_in[8];
    const float* al2  = (const float*)d_in[9];
    const float* ar2  = (const float*)d_in[10];
    const float* b2   = (const float*)d_in[11];
    float* out = (float*)d_out;

    char* p = (char*)d_ws;
    auto carve = [&](size_t bytes) {
        char* q = p;
        p += (bytes + 255) & ~size_t(255);
        return q;
    };
    __half* feat1   = (__half*)carve((size_t)N * 128 * 2);
    __half* feat2   = (__half*)carve((size_t)N * 192 * 2);
    __half* hbuf    = (__half*)carve((size_t)N * 128 * 2);
    __half* Wt1     = (__half*)carve(128 * 128 * 2);
    __half* Wt2     = (__half*)carve(192 * 128 * 2);
    float*  el      = (float*)carve((size_t)N * 4 * 4);
    float*  er      = (float*)carve((size_t)N * 4 * 4);
    int*    deg     = (int*)carve((size_t)N * 4);
    int*    row_ptr = (int*)carve((size_t)(N + 1) * 4);
    int*    cursor  = (int*)carve((size_t)N * 4);
    int*    bsum    = (int*)carve(512 * 4);
    int*    e_src   = (int*)carve((size_t)E * 4);
    int*    csr_dst = (int*)carve((size_t)E * 4);
    __half* ew      = (__half*)carve((size_t)E * 4 * 2);

    const int nb = (N + 255) / 256;  // 391

    // ---- CSR build ----
    hipMemsetAsync(deg, 0, (size_t)N * 4, stream);
    count_deg<<<(E + 255) / 256, 256, 0, stream>>>(dst, deg, E);
    block_sums<<<nb, 256, 0, stream>>>(deg, bsum, N);
    scan_bsum<<<1, 512, 0, stream>>>(bsum, nb);
    scan_final<<<nb, 256, 0, stream>>>(deg, bsum, row_ptr, cursor, csr_dst, N);
    scatter_edges_part<<<2048, 256, 0, stream>>>(src, dst, cursor, e_src, E);

    // ---- weight prep ----
    prep_w<<<320, 128, 0, stream>>>(W1, W2, Wt1, Wt2);

    // ---- layer 1 ----
    gemm_mfma<8, 128, 128, false, false, float><<<(N + 63) / 64, 256, 0, stream>>>(x, Wt1, feat1, nullptr, N);
    elr1_wave<<<(N + 3) / 4, 256, 0, stream>>>(feat1, al1, ar1, el, er);
    edge_weights<<<(E + 255) / 256, 256, 0, stream>>>(e_src, csr_dst, el, er, ew, E);
    gat_gather1<<<(N + 3) / 4, 256, 0, stream>>>(feat1, ew, row_ptr, e_src, b1, hbuf);

    // ---- layer 2 (rows gathered through inverse_idx) ----
    gemm_mfma<12, 188, 192, true, true, __half><<<(N + 63) / 64, 256, 0, stream>>>(hbuf, Wt2, feat2, inv, N);
    elr2_wave<<<(N + 3) / 4, 256, 0, stream>>>(feat2, al2, ar2, el, er);
    edge_weights<<<(E + 255) / 256, 256, 0, stream>>>(e_src, csr_dst, el, er, ew, E);
    gat_gather2<<<(N + 3) / 4, 256, 0, stream>>>(feat2, ew, row_ptr, e_src, b2, out);
}

// Round 8
// 532.416 us; speedup vs baseline: 1.1825x; 1.0925x over previous
//
#include <hip/hip_runtime.h>
#include <hip/hip_bf16.h>
#include <hip/hip_fp16.h>
#include <type_traits>

#define N_NODES 100000
#define N_EDGES 1600000

typedef _Float16 half8_t __attribute__((ext_vector_type(8)));
typedef _Float16 half4_t __attribute__((ext_vector_type(4)));
typedef float floatx4 __attribute__((ext_vector_type(4)));

// ---------------------------------------------------------------- CSR build
__global__ void count_deg(const int* __restrict__ dst, int* __restrict__ deg, int E) {
    int i = blockIdx.x * blockDim.x + threadIdx.x;
    if (i < E) atomicAdd(&deg[dst[i]], 1);
}

__global__ void block_sums(const int* __restrict__ deg, int* __restrict__ bsum, int N) {
    __shared__ int ws[4];
    const int t = threadIdx.x;
    int i = blockIdx.x * 256 + t;
    int v = (i < N) ? deg[i] : 0;
    #pragma unroll
    for (int o = 32; o; o >>= 1) v += __shfl_down(v, o, 64);
    if ((t & 63) == 0) ws[t >> 6] = v;
    __syncthreads();
    if (t == 0) bsum[blockIdx.x] = ws[0] + ws[1] + ws[2] + ws[3];
}

__global__ void scan_bsum(int* __restrict__ bsum, int nb) {
    __shared__ int sh[512];
    const int t = threadIdx.x;
    sh[t] = (t < nb) ? bsum[t] : 0;
    __syncthreads();
    for (int o = 1; o < 512; o <<= 1) {
        int v = (t >= o) ? sh[t - o] : 0;
        __syncthreads();
        sh[t] += v;
        __syncthreads();
    }
    if (t < nb) bsum[t] = sh[t];
}

__global__ void scan_final(const int* __restrict__ deg, const int* __restrict__ bsum,
                           int* __restrict__ row_ptr, int* __restrict__ cursor, int N) {
    __shared__ int ws[4];
    const int t = threadIdx.x;
    const int b = blockIdx.x;
    const int i = b * 256 + t;
    const int lane = t & 63;
    const int wid = t >> 6;
    int v = (i < N) ? deg[i] : 0;
    int x = v;
    #pragma unroll
    for (int o = 1; o < 64; o <<= 1) {
        int y = __shfl_up(x, o, 64);
        if (lane >= o) x += y;
    }
    if (lane == 63) ws[wid] = x;
    __syncthreads();
    int prefix = (b > 0) ? bsum[b - 1] : 0;
    for (int k = 0; k < wid; ++k) prefix += ws[k];
    if (i < N) {
        row_ptr[i + 1] = prefix + x;
        cursor[i] = prefix + x - v;
    }
    if (i == 0) row_ptr[0] = 0;
}

// XCD-partitioned scatter (R4→R5 measured win: kills cross-XCD CSR-line write amplification)
__global__ void scatter_edges_part(const int* __restrict__ src, const int* __restrict__ dst,
                                   int* __restrict__ cursor, int* __restrict__ e_src, int E) {
    const int part = blockIdx.x & 7;
    const int sb = blockIdx.x >> 3;
    const int nslices = gridDim.x >> 3;
    const int psz = N_NODES / 8;
    const int lo = part * psz;
    const int hi = (part == 7) ? N_NODES : lo + psz;
    const int begin = (int)((long long)E * sb / nslices);
    const int end = (int)((long long)E * (sb + 1) / nslices);
    for (int i = begin + threadIdx.x; i < end; i += blockDim.x) {
        int d = dst[i];
        if (d >= lo && d < hi) {
            int p = atomicAdd(&cursor[d], 1);
            e_src[p] = src[i];
        }
    }
}

// ---------------------------------------------------------------- W prep: transpose + fp16 + attention-projection columns
// Wt1: 144 rows x 128.  rows 0..127 = W1^T; rows 128..131 = W1·al1 (per head);
//      rows 132..135 = W1·ar1; rows 136..143 = 0.
// Wt2: 208 rows x 128.  rows 0..187 = W2^T; 188..191 = 0; rows 192..195 = W2·al2;
//      rows 196..199 = W2·ar2; rows 200..207 = 0.
__global__ void prep_w(const float* __restrict__ W1, const float* __restrict__ W2,
                       const float* __restrict__ al1, const float* __restrict__ ar1,
                       const float* __restrict__ al2, const float* __restrict__ ar2,
                       __half* __restrict__ Wt1, __half* __restrict__ Wt2) {
    const int c = blockIdx.x;
    const int k = threadIdx.x;
    if (c < 128) {
        Wt1[c * 128 + k] = __float2half(W1[k * 128 + c]);
    } else if (c < 144) {
        int j = c - 128;
        float v = 0.f;
        if (j < 8) {
            int h = j & 3;
            const float* a = (j < 4) ? al1 : ar1;
            for (int d = 0; d < 32; ++d)
                v = fmaf(W1[k * 128 + h * 32 + d], a[h * 32 + d], v);
        }
        Wt1[c * 128 + k] = __float2half(v);
    } else if (c < 336) {
        int c2 = c - 144;  // 0..191
        float v = (c2 < 188) ? W2[k * 188 + c2] : 0.f;
        Wt2[c2 * 128 + k] = __float2half(v);
    } else {
        int j = c - 336;   // 0..15 -> Wt2 rows 192..207
        float v = 0.f;
        if (j < 8) {
            int h = j & 3;
            const float* a = (j < 4) ? al2 : ar2;
            for (int d = 0; d < 47; ++d)
                v = fmaf(W2[k * 188 + h * 47 + d], a[h * 47 + d], v);
        }
        Wt2[(192 + j) * 128 + k] = __float2half(v);
    }
}

// ---------------------------------------------------------------- MFMA GEMM (+ fused el/er extra tile)
// TT = total tiles; last tile's cols 0..3 -> el[row][0..3], cols 4..7 -> er[row][0..3].
template <int TT, int NLOG, int OSTRIDE, bool PADSTORE, bool GATHER, typename AT>
__global__ __launch_bounds__(256) void gemm_mfma(
    const AT* __restrict__ A, const __half* __restrict__ Wt,
    __half* __restrict__ C, float* __restrict__ el, float* __restrict__ er,
    const int* __restrict__ gather, int N) {
    constexpr int LDA = 136;
    __shared__ _Float16 As[64 * LDA];
    __shared__ int ridx[64];
    const int tid = threadIdx.x;
    const int r0 = blockIdx.x * 64;

    if (tid < 64) {
        int row = r0 + tid;
        int pr = 0;
        if (row < N) pr = GATHER ? gather[row] : row;
        ridx[tid] = pr;
    }
    __syncthreads();

    {
        const int r = tid >> 2, q = tid & 3;
        const int src = ridx[r];
        if constexpr (std::is_same<AT, float>::value) {
            const float4* A4 = (const float4*)A;
            #pragma unroll
            for (int i = 0; i < 8; ++i) {
                float4 v = A4[(size_t)src * 32 + q * 8 + i];
                half4_t hv = {(_Float16)v.x, (_Float16)v.y, (_Float16)v.z, (_Float16)v.w};
                *(half4_t*)&As[r * LDA + q * 32 + i * 4] = hv;
            }
        } else {
            const uint4* A4 = (const uint4*)A;
            #pragma unroll
            for (int i = 0; i < 4; ++i) {
                uint4 v = A4[(size_t)src * 16 + q * 4 + i];
                *(uint4*)&As[r * LDA + q * 32 + i * 8] = v;
            }
        }
    }
    __syncthreads();

    const int lane = tid & 63;
    const int wave = tid >> 6;
    const int col = lane & 15;
    const int quad = lane >> 4;
    const int arow = wave * 16 + col;

    floatx4 acc[TT];
    #pragma unroll
    for (int t = 0; t < TT; ++t) acc[t] = (floatx4){0.f, 0.f, 0.f, 0.f};

    #pragma unroll
    for (int kc = 0; kc < 4; ++kc) {
        half8_t a = *(const half8_t*)&As[arow * LDA + kc * 32 + quad * 8];
        #pragma unroll
        for (int t = 0; t < TT; ++t) {
            half8_t b = *(const half8_t*)&Wt[(size_t)(t * 16 + col) * 128 + kc * 32 + quad * 8];
            acc[t] = __builtin_amdgcn_mfma_f32_16x16x32_f16(a, b, acc[t], 0, 0, 0);
        }
    }

    #pragma unroll
    for (int t = 0; t < TT - 1; ++t) {
        #pragma unroll
        for (int r = 0; r < 4; ++r) {
            int row = r0 + wave * 16 + quad * 4 + r;
            int c = t * 16 + col;
            if (row < N && c < NLOG) {
                int sc = PADSTORE ? (c + c / 47) : c;
                C[(size_t)row * OSTRIDE + sc] = __float2half(acc[t][r]);
            }
        }
    }
    // extra tile -> el/er
    #pragma unroll
    for (int r = 0; r < 4; ++r) {
        int row = r0 + wave * 16 + quad * 4 + r;
        if (row < N) {
            if (col < 4) el[row * 4 + col] = acc[TT - 1][r];
            else if (col < 8) er[row * 4 + (col - 4)] = acc[TT - 1][r];
        }
    }
}

// ---------------------------------------------------------------- layer-1 gather (fused edge weights)
__global__ __launch_bounds__(256) void gat_gather1(
    const __half* __restrict__ feat, const float* __restrict__ el,
    const float* __restrict__ er,
    const int* __restrict__ row_ptr, const int* __restrict__ e_src,
    const float* __restrict__ bias, __half* __restrict__ out) {
    const int t = threadIdx.x;
    const int lane = t & 63;
    const int n = blockIdx.x * 4 + (t >> 6);
    const int h = lane >> 4;
    const int start = row_ptr[n], end = row_ptr[n + 1];
    const __half2* f2 = (const __half2*)feat;
    const float ern = er[n * 4 + h];
    float ax = 0.f, ay = 0.f, s = 0.f;
    int i = start;
    for (; i + 4 <= end; i += 4) {
        int sv0 = e_src[i + 0], sv1 = e_src[i + 1], sv2 = e_src[i + 2], sv3 = e_src[i + 3];
        float e0 = el[sv0 * 4 + h] + ern;
        float e1 = el[sv1 * 4 + h] + ern;
        float e2 = el[sv2 * 4 + h] + ern;
        float e3 = el[sv3 * 4 + h] + ern;
        float w0 = __expf(fmaxf(e0, 0.2f * e0));
        float w1 = __expf(fmaxf(e1, 0.2f * e1));
        float w2 = __expf(fmaxf(e2, 0.2f * e2));
        float w3 = __expf(fmaxf(e3, 0.2f * e3));
        __half2 f0 = f2[(size_t)sv0 * 64 + lane];
        __half2 f1 = f2[(size_t)sv1 * 64 + lane];
        __half2 f2v = f2[(size_t)sv2 * 64 + lane];
        __half2 f3 = f2[(size_t)sv3 * 64 + lane];
        float2 g0 = __half22float2(f0), g1 = __half22float2(f1);
        float2 g2 = __half22float2(f2v), g3 = __half22float2(f3);
        s += (w0 + w1) + (w2 + w3);
        ax += w0 * g0.x + w1 * g1.x + w2 * g2.x + w3 * g3.x;
        ay += w0 * g0.y + w1 * g1.y + w2 * g2.y + w3 * g3.y;
    }
    for (; i < end; ++i) {
        int sv = e_src[i];
        float e = el[sv * 4 + h] + ern;
        float ww = __expf(fmaxf(e, 0.2f * e));
        float2 g = __half22float2(f2[(size_t)sv * 64 + lane]);
        s += ww;
        ax += ww * g.x;
        ay += ww * g.y;
    }
    float inv = 1.f / fmaxf(s, 1e-9f);
    float ox = ax * inv + bias[lane * 2 + 0];
    float oy = ay * inv + bias[lane * 2 + 1];
    ox = (ox > 0.f) ? ox : (__expf(ox) - 1.f);
    oy = (oy > 0.f) ? oy : (__expf(oy) - 1.f);
    ((__half2*)out)[(size_t)n * 64 + lane] = __floats2half2_rn(ox, oy);
}

// ---------------------------------------------------------------- layer-2 gather (fused edge weights)
__global__ __launch_bounds__(256) void gat_gather2(
    const __half* __restrict__ feat, const float* __restrict__ el,
    const float* __restrict__ er,
    const int* __restrict__ row_ptr, const int* __restrict__ e_src,
    const float* __restrict__ bias, float* __restrict__ out) {
    const int t = threadIdx.x;
    const int lane = t & 63;
    const int n = blockIdx.x * 4 + (t >> 6);
    if (lane < 48) {
        const int h = lane / 12;
        const int q = lane - h * 12;
        const int start = row_ptr[n], end = row_ptr[n + 1];
        const half4_t* f4 = (const half4_t*)feat;
        const float ern = er[n * 4 + h];
        float a0 = 0.f, a1 = 0.f, a2 = 0.f, a3 = 0.f, s = 0.f;
        int i = start;
        for (; i + 4 <= end; i += 4) {
            int sv0 = e_src[i + 0], sv1 = e_src[i + 1], sv2 = e_src[i + 2], sv3 = e_src[i + 3];
            float e0 = el[sv0 * 4 + h] + ern;
            float e1 = el[sv1 * 4 + h] + ern;
            float e2 = el[sv2 * 4 + h] + ern;
            float e3 = el[sv3 * 4 + h] + ern;
            float w0 = __expf(fmaxf(e0, 0.2f * e0));
            float w1 = __expf(fmaxf(e1, 0.2f * e1));
            float w2 = __expf(fmaxf(e2, 0.2f * e2));
            float w3 = __expf(fmaxf(e3, 0.2f * e3));
            half4_t f0 = f4[(size_t)sv0 * 48 + lane];
            half4_t f1 = f4[(size_t)sv1 * 48 + lane];
            half4_t f2 = f4[(size_t)sv2 * 48 + lane];
            half4_t f3 = f4[(size_t)sv3 * 48 + lane];
            s += (w0 + w1) + (w2 + w3);
            a0 += w0 * (float)f0[0] + w1 * (float)f1[0] + w2 * (float)f2[0] + w3 * (float)f3[0];
            a1 += w0 * (float)f0[1] + w1 * (float)f1[1] + w2 * (float)f2[1] + w3 * (float)f3[1];
            a2 += w0 * (float)f0[2] + w1 * (float)f1[2] + w2 * (float)f2[2] + w3 * (float)f3[2];
            a3 += w0 * (float)f0[3] + w1 * (float)f1[3] + w2 * (float)f2[3] + w3 * (float)f3[3];
        }
        for (; i < end; ++i) {
            int sv = e_src[i];
            float e = el[sv * 4 + h] + ern;
            float ww = __expf(fmaxf(e, 0.2f * e));
            half4_t f0 = f4[(size_t)sv * 48 + lane];
            s += ww;
            a0 += ww * (float)f0[0];
            a1 += ww * (float)f0[1];
            a2 += ww * (float)f0[2];
            a3 += ww * (float)f0[3];
        }
        if (q == 11) a3 = 0.f;
        float inv = 1.f / fmaxf(s, 1e-9f);
        const int d0 = q * 4;
        float b0 = bias[h * 47 + d0 + 0];
        float b1 = bias[h * 47 + d0 + 1];
        float b2 = bias[h * 47 + d0 + 2];
        float b3 = (d0 + 3 < 47) ? bias[h * 47 + d0 + 3] : 0.f;
        float r0 = a0 * inv + b0;
        float r1 = a1 * inv + b1;
        float r2 = a2 * inv + b2;
        float r3 = a3 * inv + b3;
        float t0 = r0 + __shfl(r0, lane + 12, 64) + __shfl(r0, lane + 24, 64) + __shfl(r0, lane + 36, 64);
        float t1 = r1 + __shfl(r1, lane + 12, 64) + __shfl(r1, lane + 24, 64) + __shfl(r1, lane + 36, 64);
        float t2 = r2 + __shfl(r2, lane + 12, 64) + __shfl(r2, lane + 24, 64) + __shfl(r2, lane + 36, 64);
        float t3 = r3 + __shfl(r3, lane + 12, 64) + __shfl(r3, lane + 24, 64) + __shfl(r3, lane + 36, 64);
        if (h == 0) {
            size_t base = (size_t)n * 47 + d0;
            out[base + 0] = 0.25f * t0;
            out[base + 1] = 0.25f * t1;
            out[base + 2] = 0.25f * t2;
            if (d0 + 3 < 47) out[base + 3] = 0.25f * t3;
        }
    }
}

// ---------------------------------------------------------------- launcher
extern "C" void kernel_launch(void* const* d_in, const int* in_sizes, int n_in,
                              void* d_out, int out_size, void* d_ws, size_t ws_size,
                              hipStream_t stream) {
    const int N = N_NODES, E = N_EDGES;
    const float* x    = (const float*)d_in[0];
    const int*   src  = (const int*)d_in[1];
    const int*   dst  = (const int*)d_in[2];
    const int*   inv  = (const int*)d_in[3];
    const float* W1   = (const float*)d_in[4];
    const float* al1  = (const float*)d_in[5];
    const float* ar1  = (const float*)d_in[6];
    const float* b1   = (const float*)d_in[7];
    const float* W2   = (const float*)d_in[8];
    const float* al2  = (const float*)d_in[9];
    const float* ar2  = (const float*)d_in[10];
    const float* b2   = (const float*)d_in[11];
    float* out = (float*)d_out;

    char* p = (char*)d_ws;
    auto carve = [&](size_t bytes) {
        char* q = p;
        p += (bytes + 255) & ~size_t(255);
        return q;
    };
    __half* feat1   = (__half*)carve((size_t)N * 128 * 2);
    __half* feat2   = (__half*)carve((size_t)N * 192 * 2);
    __half* hbuf    = (__half*)carve((size_t)N * 128 * 2);
    __half* Wt1     = (__half*)carve(144 * 128 * 2);
    __half* Wt2     = (__half*)carve(208 * 128 * 2);
    float*  el      = (float*)carve((size_t)N * 4 * 4);
    float*  er      = (float*)carve((size_t)N * 4 * 4);
    int*    deg     = (int*)carve((size_t)N * 4);
    int*    row_ptr = (int*)carve((size_t)(N + 1) * 4);
    int*    cursor  = (int*)carve((size_t)N * 4);
    int*    bsum    = (int*)carve(512 * 4);
    int*    e_src   = (int*)carve((size_t)E * 4);

    const int nb = (N + 255) / 256;  // 391

    // ---- CSR build ----
    hipMemsetAsync(deg, 0, (size_t)N * 4, stream);
    count_deg<<<(E + 255) / 256, 256, 0, stream>>>(dst, deg, E);
    block_sums<<<nb, 256, 0, stream>>>(deg, bsum, N);
    scan_bsum<<<1, 512, 0, stream>>>(bsum, nb);
    scan_final<<<nb, 256, 0, stream>>>(deg, bsum, row_ptr, cursor, N);
    scatter_edges_part<<<2048, 256, 0, stream>>>(src, dst, cursor, e_src, E);

    // ---- weight prep (transpose + fp16 + attention-projection cols) ----
    prep_w<<<352, 128, 0, stream>>>(W1, W2, al1, ar1, al2, ar2, Wt1, Wt2);

    // ---- layer 1 ----
    gemm_mfma<9, 128, 128, false, false, float><<<(N + 63) / 64, 256, 0, stream>>>(
        x, Wt1, feat1, el, er, nullptr, N);
    gat_gather1<<<(N + 3) / 4, 256, 0, stream>>>(feat1, el, er, row_ptr, e_src, b1, hbuf);

    // ---- layer 2 (rows gathered through inverse_idx) ----
    gemm_mfma<13, 188, 192, true, true, __half><<<(N + 63) / 64, 256, 0, stream>>>(
        hbuf, Wt2, feat2, el, er, inv, N);
    gat_gather2<<<(N + 3) / 4, 256, 0, stream>>>(feat2, el, er, row_ptr, e_src, b2, out);
}

// Round 9
// 521.074 us; speedup vs baseline: 1.2082x; 1.0218x over previous
//
#include <hip/hip_runtime.h>
#include <hip/hip_bf16.h>
#include <hip/hip_fp16.h>
#include <type_traits>

#define N_NODES 100000
#define N_EDGES 1600000

typedef _Float16 half8_t __attribute__((ext_vector_type(8)));
typedef _Float16 half4_t __attribute__((ext_vector_type(4)));
typedef float floatx4 __attribute__((ext_vector_type(4)));

// ---------------------------------------------------------------- fused count_deg + prep_w
// blocks 0..6249: degree histogram.  blocks 6250..6601: weight transpose/pack.
// Wt1: 144 rows x 128. rows 0..127 = W1^T; 128..131 = W1·al1; 132..135 = W1·ar1; 136..143 = 0.
// Wt2: 208 rows x 128. rows 0..187 = W2^T; 188..191 = 0; 192..195 = W2·al2; 196..199 = W2·ar2; 200..207 = 0.
__global__ void csr_prep(const int* __restrict__ dst, int* __restrict__ deg, int E,
                         const float* __restrict__ W1, const float* __restrict__ W2,
                         const float* __restrict__ al1, const float* __restrict__ ar1,
                         const float* __restrict__ al2, const float* __restrict__ ar2,
                         __half* __restrict__ Wt1, __half* __restrict__ Wt2) {
    const int b = blockIdx.x;
    if (b < 6250) {
        int i = b * 256 + threadIdx.x;
        if (i < E) atomicAdd(&deg[dst[i]], 1);
        return;
    }
    const int c = b - 6250;           // 0..351
    const int k = threadIdx.x;
    if (k >= 128) return;
    if (c < 128) {
        Wt1[c * 128 + k] = __float2half(W1[k * 128 + c]);
    } else if (c < 144) {
        int j = c - 128;
        float v = 0.f;
        if (j < 8) {
            int h = j & 3;
            const float* a = (j < 4) ? al1 : ar1;
            for (int d = 0; d < 32; ++d)
                v = fmaf(W1[k * 128 + h * 32 + d], a[h * 32 + d], v);
        }
        Wt1[c * 128 + k] = __float2half(v);
    } else if (c < 336) {
        int c2 = c - 144;  // 0..191
        float v = (c2 < 188) ? W2[k * 188 + c2] : 0.f;
        Wt2[c2 * 128 + k] = __float2half(v);
    } else {
        int j = c - 336;   // 0..15 -> Wt2 rows 192..207
        float v = 0.f;
        if (j < 8) {
            int h = j & 3;
            const float* a = (j < 4) ? al2 : ar2;
            for (int d = 0; d < 47; ++d)
                v = fmaf(W2[k * 188 + h * 47 + d], a[h * 47 + d], v);
        }
        Wt2[(192 + j) * 128 + k] = __float2half(v);
    }
}

__global__ void block_sums(const int* __restrict__ deg, int* __restrict__ bsum, int N) {
    __shared__ int ws[4];
    const int t = threadIdx.x;
    int i = blockIdx.x * 256 + t;
    int v = (i < N) ? deg[i] : 0;
    #pragma unroll
    for (int o = 32; o; o >>= 1) v += __shfl_down(v, o, 64);
    if ((t & 63) == 0) ws[t >> 6] = v;
    __syncthreads();
    if (t == 0) bsum[blockIdx.x] = ws[0] + ws[1] + ws[2] + ws[3];
}

__global__ void scan_bsum(int* __restrict__ bsum, int nb) {
    __shared__ int sh[512];
    const int t = threadIdx.x;
    sh[t] = (t < nb) ? bsum[t] : 0;
    __syncthreads();
    for (int o = 1; o < 512; o <<= 1) {
        int v = (t >= o) ? sh[t - o] : 0;
        __syncthreads();
        sh[t] += v;
        __syncthreads();
    }
    if (t < nb) bsum[t] = sh[t];
}

__global__ void scan_final(const int* __restrict__ deg, const int* __restrict__ bsum,
                           int* __restrict__ row_ptr, int* __restrict__ cursor, int N) {
    __shared__ int ws[4];
    const int t = threadIdx.x;
    const int b = blockIdx.x;
    const int i = b * 256 + t;
    const int lane = t & 63;
    const int wid = t >> 6;
    int v = (i < N) ? deg[i] : 0;
    int x = v;
    #pragma unroll
    for (int o = 1; o < 64; o <<= 1) {
        int y = __shfl_up(x, o, 64);
        if (lane >= o) x += y;
    }
    if (lane == 63) ws[wid] = x;
    __syncthreads();
    int prefix = (b > 0) ? bsum[b - 1] : 0;
    for (int k = 0; k < wid; ++k) prefix += ws[k];
    if (i < N) {
        row_ptr[i + 1] = prefix + x;
        cursor[i] = prefix + x - v;
    }
    if (i == 0) row_ptr[0] = 0;
}

// XCD-partitioned scatter (R4→R5 measured win: kills cross-XCD CSR-line write amplification)
__global__ void scatter_edges_part(const int* __restrict__ src, const int* __restrict__ dst,
                                   int* __restrict__ cursor, int* __restrict__ e_src, int E) {
    const int part = blockIdx.x & 7;
    const int sb = blockIdx.x >> 3;
    const int nslices = gridDim.x >> 3;
    const int psz = N_NODES / 8;
    const int lo = part * psz;
    const int hi = (part == 7) ? N_NODES : lo + psz;
    const int begin = (int)((long long)E * sb / nslices);
    const int end = (int)((long long)E * (sb + 1) / nslices);
    for (int i = begin + threadIdx.x; i < end; i += blockDim.x) {
        int d = dst[i];
        if (d >= lo && d < hi) {
            int p = atomicAdd(&cursor[d], 1);
            e_src[p] = src[i];
        }
    }
}

// ---------------------------------------------------------------- MFMA GEMM (+ fused el/er extra tile)
// TT = total tiles; last tile: cols 0..3 = el per head, cols 4..7 = er per head.
// EMBED (layer2): el stored fp16 into feat pad slots (col h*48+47) — rides the row's
//   cache lines, zero marginal fetch in the gather.  else (layer1): el -> packed fp16 table.
template <int TT, int NLOG, int OSTRIDE, bool EMBED, bool GATHER, typename AT>
__global__ __launch_bounds__(256) void gemm_mfma(
    const AT* __restrict__ A, const __half* __restrict__ Wt,
    __half* __restrict__ C, __half* __restrict__ elh, float* __restrict__ er,
    const int* __restrict__ gather, int N) {
    constexpr int LDA = 136;
    __shared__ _Float16 As[64 * LDA];
    __shared__ int ridx[64];
    const int tid = threadIdx.x;
    const int r0 = blockIdx.x * 64;

    if (tid < 64) {
        int row = r0 + tid;
        int pr = 0;
        if (row < N) pr = GATHER ? gather[row] : row;
        ridx[tid] = pr;
    }
    __syncthreads();

    {
        const int r = tid >> 2, q = tid & 3;
        const int src = ridx[r];
        if constexpr (std::is_same<AT, float>::value) {
            const float4* A4 = (const float4*)A;
            #pragma unroll
            for (int i = 0; i < 8; ++i) {
                float4 v = A4[(size_t)src * 32 + q * 8 + i];
                half4_t hv = {(_Float16)v.x, (_Float16)v.y, (_Float16)v.z, (_Float16)v.w};
                *(half4_t*)&As[r * LDA + q * 32 + i * 4] = hv;
            }
        } else {
            const uint4* A4 = (const uint4*)A;
            #pragma unroll
            for (int i = 0; i < 4; ++i) {
                uint4 v = A4[(size_t)src * 16 + q * 4 + i];
                *(uint4*)&As[r * LDA + q * 32 + i * 8] = v;
            }
        }
    }
    __syncthreads();

    const int lane = tid & 63;
    const int wave = tid >> 6;
    const int col = lane & 15;
    const int quad = lane >> 4;
    const int arow = wave * 16 + col;

    floatx4 acc[TT];
    #pragma unroll
    for (int t = 0; t < TT; ++t) acc[t] = (floatx4){0.f, 0.f, 0.f, 0.f};

    #pragma unroll
    for (int kc = 0; kc < 4; ++kc) {
        half8_t a = *(const half8_t*)&As[arow * LDA + kc * 32 + quad * 8];
        #pragma unroll
        for (int t = 0; t < TT; ++t) {
            half8_t b = *(const half8_t*)&Wt[(size_t)(t * 16 + col) * 128 + kc * 32 + quad * 8];
            acc[t] = __builtin_amdgcn_mfma_f32_16x16x32_f16(a, b, acc[t], 0, 0, 0);
        }
    }

    #pragma unroll
    for (int t = 0; t < TT - 1; ++t) {
        #pragma unroll
        for (int r = 0; r < 4; ++r) {
            int row = r0 + wave * 16 + quad * 4 + r;
            int c = t * 16 + col;
            if (row < N && c < NLOG) {
                int sc = EMBED ? (c + c / 47) : c;   // per-head pad: storage col = h*48+d
                C[(size_t)row * OSTRIDE + sc] = __float2half(acc[t][r]);
            }
        }
    }
    // extra tile -> el/er
    #pragma unroll
    for (int r = 0; r < 4; ++r) {
        int row = r0 + wave * 16 + quad * 4 + r;
        if (row < N) {
            if (col < 4) {
                if constexpr (EMBED)
                    C[(size_t)row * OSTRIDE + col * 48 + 47] = __float2half(acc[TT - 1][r]);
                else
                    elh[row * 4 + col] = __float2half(acc[TT - 1][r]);
            } else if (col < 8) {
                er[row * 4 + (col - 4)] = acc[TT - 1][r];
            }
        }
    }
}

// ---------------------------------------------------------------- layer-1 gather (fused edge weights, fp16 el table)
__global__ __launch_bounds__(256) void gat_gather1(
    const __half* __restrict__ feat, const __half* __restrict__ elh,
    const float* __restrict__ er,
    const int* __restrict__ row_ptr, const int* __restrict__ e_src,
    const float* __restrict__ bias, __half* __restrict__ out) {
    const int t = threadIdx.x;
    const int lane = t & 63;
    const int n = blockIdx.x * 4 + (t >> 6);
    const int h = lane >> 4;
    const int start = row_ptr[n], end = row_ptr[n + 1];
    const __half2* f2 = (const __half2*)feat;
    const float ern = er[n * 4 + h];
    float ax = 0.f, ay = 0.f, s = 0.f;
    int i = start;
    for (; i + 4 <= end; i += 4) {
        int sv0 = e_src[i + 0], sv1 = e_src[i + 1], sv2 = e_src[i + 2], sv3 = e_src[i + 3];
        float e0 = __half2float(elh[sv0 * 4 + h]) + ern;
        float e1 = __half2float(elh[sv1 * 4 + h]) + ern;
        float e2 = __half2float(elh[sv2 * 4 + h]) + ern;
        float e3 = __half2float(elh[sv3 * 4 + h]) + ern;
        float w0 = __expf(fmaxf(e0, 0.2f * e0));
        float w1 = __expf(fmaxf(e1, 0.2f * e1));
        float w2 = __expf(fmaxf(e2, 0.2f * e2));
        float w3 = __expf(fmaxf(e3, 0.2f * e3));
        __half2 f0 = f2[(size_t)sv0 * 64 + lane];
        __half2 f1 = f2[(size_t)sv1 * 64 + lane];
        __half2 f2v = f2[(size_t)sv2 * 64 + lane];
        __half2 f3 = f2[(size_t)sv3 * 64 + lane];
        float2 g0 = __half22float2(f0), g1 = __half22float2(f1);
        float2 g2 = __half22float2(f2v), g3 = __half22float2(f3);
        s += (w0 + w1) + (w2 + w3);
        ax += w0 * g0.x + w1 * g1.x + w2 * g2.x + w3 * g3.x;
        ay += w0 * g0.y + w1 * g1.y + w2 * g2.y + w3 * g3.y;
    }
    for (; i < end; ++i) {
        int sv = e_src[i];
        float e = __half2float(elh[sv * 4 + h]) + ern;
        float ww = __expf(fmaxf(e, 0.2f * e));
        float2 g = __half22float2(f2[(size_t)sv * 64 + lane]);
        s += ww;
        ax += ww * g.x;
        ay += ww * g.y;
    }
    float inv = 1.f / fmaxf(s, 1e-9f);
    float ox = ax * inv + bias[lane * 2 + 0];
    float oy = ay * inv + bias[lane * 2 + 1];
    ox = (ox > 0.f) ? ox : (__expf(ox) - 1.f);
    oy = (oy > 0.f) ? oy : (__expf(oy) - 1.f);
    ((__half2*)out)[(size_t)n * 64 + lane] = __floats2half2_rn(ox, oy);
}

// ---------------------------------------------------------------- layer-2 gather (el embedded in feat pad slots)
__global__ __launch_bounds__(256) void gat_gather2(
    const __half* __restrict__ feat, const float* __restrict__ er,
    const int* __restrict__ row_ptr, const int* __restrict__ e_src,
    const float* __restrict__ bias, float* __restrict__ out) {
    const int t = threadIdx.x;
    const int lane = t & 63;
    const int n = blockIdx.x * 4 + (t >> 6);
    if (lane < 48) {
        const int h = lane / 12;
        const int q = lane - h * 12;
        const int g11 = h * 12 + 11;         // lane holding el_h in f[3]
        const int start = row_ptr[n], end = row_ptr[n + 1];
        const half4_t* f4 = (const half4_t*)feat;
        const float ern = er[n * 4 + h];
        float a0 = 0.f, a1 = 0.f, a2 = 0.f, a3 = 0.f, s = 0.f;
        int i = start;
        for (; i + 4 <= end; i += 4) {
            int sv0 = e_src[i + 0], sv1 = e_src[i + 1], sv2 = e_src[i + 2], sv3 = e_src[i + 3];
            half4_t f0 = f4[(size_t)sv0 * 48 + lane];
            half4_t f1 = f4[(size_t)sv1 * 48 + lane];
            half4_t f2 = f4[(size_t)sv2 * 48 + lane];
            half4_t f3 = f4[(size_t)sv3 * 48 + lane];
            float e0 = __shfl((float)f0[3], g11, 64) + ern;
            float e1 = __shfl((float)f1[3], g11, 64) + ern;
            float e2 = __shfl((float)f2[3], g11, 64) + ern;
            float e3 = __shfl((float)f3[3], g11, 64) + ern;
            float w0 = __expf(fmaxf(e0, 0.2f * e0));
            float w1 = __expf(fmaxf(e1, 0.2f * e1));
            float w2 = __expf(fmaxf(e2, 0.2f * e2));
            float w3 = __expf(fmaxf(e3, 0.2f * e3));
            s += (w0 + w1) + (w2 + w3);
            a0 += w0 * (float)f0[0] + w1 * (float)f1[0] + w2 * (float)f2[0] + w3 * (float)f3[0];
            a1 += w0 * (float)f0[1] + w1 * (float)f1[1] + w2 * (float)f2[1] + w3 * (float)f3[1];
            a2 += w0 * (float)f0[2] + w1 * (float)f1[2] + w2 * (float)f2[2] + w3 * (float)f3[2];
            a3 += w0 * (float)f0[3] + w1 * (float)f1[3] + w2 * (float)f2[3] + w3 * (float)f3[3];
        }
        for (; i < end; ++i) {
            int sv = e_src[i];
            half4_t f0 = f4[(size_t)sv * 48 + lane];
            float e = __shfl((float)f0[3], g11, 64) + ern;
            float ww = __expf(fmaxf(e, 0.2f * e));
            s += ww;
            a0 += ww * (float)f0[0];
            a1 += ww * (float)f0[1];
            a2 += ww * (float)f0[2];
            a3 += ww * (float)f0[3];
        }
        if (q == 11) a3 = 0.f;               // pad col (holds el) — mask from accumulator
        float inv = 1.f / fmaxf(s, 1e-9f);
        const int d0 = q * 4;
        float b0 = bias[h * 47 + d0 + 0];
        float b1 = bias[h * 47 + d0 + 1];
        float b2 = bias[h * 47 + d0 + 2];
        float b3 = (d0 + 3 < 47) ? bias[h * 47 + d0 + 3] : 0.f;
        float r0 = a0 * inv + b0;
        float r1 = a1 * inv + b1;
        float r2 = a2 * inv + b2;
        float r3 = a3 * inv + b3;
        float t0 = r0 + __shfl(r0, lane + 12, 64) + __shfl(r0, lane + 24, 64) + __shfl(r0, lane + 36, 64);
        float t1 = r1 + __shfl(r1, lane + 12, 64) + __shfl(r1, lane + 24, 64) + __shfl(r1, lane + 36, 64);
        float t2 = r2 + __shfl(r2, lane + 12, 64) + __shfl(r2, lane + 24, 64) + __shfl(r2, lane + 36, 64);
        float t3 = r3 + __shfl(r3, lane + 12, 64) + __shfl(r3, lane + 24, 64) + __shfl(r3, lane + 36, 64);
        if (h == 0) {
            size_t base = (size_t)n * 47 + d0;
            out[base + 0] = 0.25f * t0;
            out[base + 1] = 0.25f * t1;
            out[base + 2] = 0.25f * t2;
            if (d0 + 3 < 47) out[base + 3] = 0.25f * t3;
        }
    }
}

// ---------------------------------------------------------------- launcher
extern "C" void kernel_launch(void* const* d_in, const int* in_sizes, int n_in,
                              void* d_out, int out_size, void* d_ws, size_t ws_size,
                              hipStream_t stream) {
    const int N = N_NODES, E = N_EDGES;
    const float* x    = (const float*)d_in[0];
    const int*   src  = (const int*)d_in[1];
    const int*   dst  = (const int*)d_in[2];
    const int*   inv  = (const int*)d_in[3];
    const float* W1   = (const float*)d_in[4];
    const float* al1  = (const float*)d_in[5];
    const float* ar1  = (const float*)d_in[6];
    const float* b1   = (const float*)d_in[7];
    const float* W2   = (const float*)d_in[8];
    const float* al2  = (const float*)d_in[9];
    const float* ar2  = (const float*)d_in[10];
    const float* b2   = (const float*)d_in[11];
    float* out = (float*)d_out;

    char* p = (char*)d_ws;
    auto carve = [&](size_t bytes) {
        char* q = p;
        p += (bytes + 255) & ~size_t(255);
        return q;
    };
    __half* feat1   = (__half*)carve((size_t)N * 128 * 2);
    __half* feat2   = (__half*)carve((size_t)N * 192 * 2);  // padded h*48+d; pad slot h*48+47 = el2(h) fp16
    __half* hbuf    = (__half*)carve((size_t)N * 128 * 2);
    __half* Wt1     = (__half*)carve(144 * 128 * 2);
    __half* Wt2     = (__half*)carve(208 * 128 * 2);
    __half* elh1    = (__half*)carve((size_t)N * 4 * 2);
    float*  er      = (float*)carve((size_t)N * 4 * 4);
    int*    deg     = (int*)carve((size_t)N * 4);
    int*    row_ptr = (int*)carve((size_t)(N + 1) * 4);
    int*    cursor  = (int*)carve((size_t)N * 4);
    int*    bsum    = (int*)carve(512 * 4);
    int*    e_src   = (int*)carve((size_t)E * 4);

    const int nb = (N + 255) / 256;  // 391

    // ---- CSR build + weight prep (fused count_deg + prep_w) ----
    hipMemsetAsync(deg, 0, (size_t)N * 4, stream);
    csr_prep<<<6250 + 352, 256, 0, stream>>>(dst, deg, E, W1, W2, al1, ar1, al2, ar2, Wt1, Wt2);
    block_sums<<<nb, 256, 0, stream>>>(deg, bsum, N);
    scan_bsum<<<1, 512, 0, stream>>>(bsum, nb);
    scan_final<<<nb, 256, 0, stream>>>(deg, bsum, row_ptr, cursor, N);
    scatter_edges_part<<<2048, 256, 0, stream>>>(src, dst, cursor, e_src, E);

    // ---- layer 1 ----
    gemm_mfma<9, 128, 128, false, false, float><<<(N + 63) / 64, 256, 0, stream>>>(
        x, Wt1, feat1, elh1, er, nullptr, N);
    gat_gather1<<<(N + 3) / 4, 256, 0, stream>>>(feat1, elh1, er, row_ptr, e_src, b1, hbuf);

    // ---- layer 2 (rows gathered through inverse_idx; el2 embedded in feat2 pad) ----
    gemm_mfma<13, 188, 192, true, true, __half><<<(N + 63) / 64, 256, 0, stream>>>(
        hbuf, Wt2, feat2, nullptr, er, inv, N);
    gat_gather2<<<(N + 3) / 4, 256, 0, stream>>>(feat2, er, row_ptr, e_src, b2, out);
}